// Round 1
// baseline (524.734 us; speedup 1.0000x reference)
//
#include <hip/hip_runtime.h>

typedef __attribute__((ext_vector_type(8))) short s16x8;
typedef __attribute__((ext_vector_type(4))) float f32x4;

#define WS_SEG 67108864  // 64 MiB per region: [t/O][Q][K][Vt]

static __device__ __forceinline__ unsigned short f2bf(float f) {
    unsigned int u = __builtin_bit_cast(unsigned int, f);
    u = (u + 0x7FFFu + ((u >> 16) & 1u)) >> 16;   // RNE
    return (unsigned short)u;
}
static __device__ __forceinline__ unsigned int pack2(float a, float b) {
    return (unsigned int)f2bf(a) | ((unsigned int)f2bf(b) << 16);
}

// ---------------------------------------------------------------------------
// Kernel 0: patch gather  x[B=2,C=256,H=256,W=256] f32 -> t bf16 [512*256][256]
// t[(n*256+c)*256 + e] = x[b, c, (p>>4)*16 + (e>>4), (p&15)*16 + (e&15)],
// n = b*256+p.
// ---------------------------------------------------------------------------
__global__ __launch_bounds__(256) void gather_bf16(const float* __restrict__ x,
                                                   unsigned short* __restrict__ t) {
    int q = (blockIdx.x * 256 + threadIdx.x) * 4;          // flat t index
    int e = q & 255, c = (q >> 8) & 255, n = q >> 16;
    int b = n >> 8, p = n & 255;
    int xi = ((b * 256 + c) * 256 + (p >> 4) * 16 + (e >> 4)) * 256 + (p & 15) * 16 + (e & 15);
    float4 v = *reinterpret_cast<const float4*>(x + xi);
    uint2 o = { pack2(v.x, v.y), pack2(v.z, v.w) };
    *reinterpret_cast<uint2*>(t + q) = o;
}

// ---------------------------------------------------------------------------
// Shared GEMM:  C[M=131072][N] = A(bf16,[M][256]) @ W(f32,[N][256])^T + bias
// tile 128x64, BK=64, 4 waves (2x2), each wave 64x32 via 16x16x32 MFMA.
// MODE 0: N=768, scatter to Q/K [n][h][c][64] and Vt [n][h][64][c] (bf16)
// MODE 1: N=256, scatter to out f32 [b][c][p][e]
// ---------------------------------------------------------------------------
template<int MODE>
__global__ __launch_bounds__(256) void gemm_bf16(
    const unsigned short* __restrict__ A, const float* __restrict__ W,
    const float* __restrict__ bias,
    unsigned short* __restrict__ Qo, unsigned short* __restrict__ Ko,
    unsigned short* __restrict__ Vt, float* __restrict__ Out)
{
    __shared__ __align__(16) unsigned short As[128][72];  // +8 pad: 2-way banks
    __shared__ __align__(16) unsigned short Bs[64][72];

    const int t = threadIdx.x;
    const int w = t >> 6, lane = t & 63;
    const int wm = w >> 1, wn = w & 1;
    const int lr = lane & 15, lk = lane >> 4;
    const int bm = blockIdx.x, bn = blockIdx.y;

    f32x4 acc[4][2] = {};

    const unsigned short* Ag = A + (bm * 128 + (t >> 1)) * 256 + (t & 1) * 32;
    const float* Wg = W + (bn * 64 + (t >> 2)) * 256 + (t & 3) * 16;
    unsigned short* Asw = &As[t >> 1][(t & 1) * 32];
    unsigned short* Bsw = &Bs[t >> 2][(t & 3) * 16];

    for (int kk = 0; kk < 4; ++kk) {
        uint4 a0 = reinterpret_cast<const uint4*>(Ag)[0];
        uint4 a1 = reinterpret_cast<const uint4*>(Ag)[1];
        uint4 a2 = reinterpret_cast<const uint4*>(Ag)[2];
        uint4 a3 = reinterpret_cast<const uint4*>(Ag)[3];
        float4 f0 = reinterpret_cast<const float4*>(Wg)[0];
        float4 f1 = reinterpret_cast<const float4*>(Wg)[1];
        float4 f2 = reinterpret_cast<const float4*>(Wg)[2];
        float4 f3 = reinterpret_cast<const float4*>(Wg)[3];
        reinterpret_cast<uint4*>(Asw)[0] = a0;
        reinterpret_cast<uint4*>(Asw)[1] = a1;
        reinterpret_cast<uint4*>(Asw)[2] = a2;
        reinterpret_cast<uint4*>(Asw)[3] = a3;
        uint4 b0 = { pack2(f0.x, f0.y), pack2(f0.z, f0.w), pack2(f1.x, f1.y), pack2(f1.z, f1.w) };
        uint4 b1 = { pack2(f2.x, f2.y), pack2(f2.z, f2.w), pack2(f3.x, f3.y), pack2(f3.z, f3.w) };
        reinterpret_cast<uint4*>(Bsw)[0] = b0;
        reinterpret_cast<uint4*>(Bsw)[1] = b1;
        __syncthreads();

        #pragma unroll
        for (int kc = 0; kc < 2; ++kc) {
            s16x8 af[4], bf[2];
            #pragma unroll
            for (int fm = 0; fm < 4; ++fm)
                af[fm] = *reinterpret_cast<const s16x8*>(&As[wm * 64 + fm * 16 + lr][kc * 32 + lk * 8]);
            #pragma unroll
            for (int fn = 0; fn < 2; ++fn)
                bf[fn] = *reinterpret_cast<const s16x8*>(&Bs[wn * 32 + fn * 16 + lr][kc * 32 + lk * 8]);
            #pragma unroll
            for (int fm = 0; fm < 4; ++fm)
                #pragma unroll
                for (int fn = 0; fn < 2; ++fn)
                    acc[fm][fn] = __builtin_amdgcn_mfma_f32_16x16x32_bf16(af[fm], bf[fn], acc[fm][fn], 0, 0, 0);
        }
        __syncthreads();
        Ag += 64; Wg += 64;
    }

    const int rbase = bm * 128 + wm * 64;
    const int cbase = bn * 64 + wn * 32;
    #pragma unroll
    for (int fn = 0; fn < 2; ++fn) {
        const int colg = cbase + fn * 16 + lr;
        const float bv = bias[colg];
        #pragma unroll
        for (int fm = 0; fm < 4; ++fm) {
            #pragma unroll
            for (int j = 0; j < 4; ++j) {
                const int rg = rbase + fm * 16 + lk * 4 + j;   // row = n*256 + c
                const float val = acc[fm][fn][j] + bv;
                if (MODE == 0) {
                    const int n = rg >> 8, c = rg & 255;
                    const int which = colg >> 8, rem = colg & 255;
                    const int h = rem >> 6, d = rem & 63;
                    if (which == 0)      Qo[((n * 4 + h) * 256 + c) * 64 + d] = f2bf(val);
                    else if (which == 1) Ko[((n * 4 + h) * 256 + c) * 64 + d] = f2bf(val);
                    else                 Vt[((n * 4 + h) * 64 + d) * 256 + c] = f2bf(val);
                } else {
                    const int n = rg >> 8, c = rg & 255;
                    const int b = n >> 8, p = n & 255;
                    Out[((b * 256 + c) * 256 + p) * 256 + colg] = val;
                }
            }
        }
    }
}

// ---------------------------------------------------------------------------
// Kernel 2: attention. One block per (n,h); 4 waves.
// K,Vt staged in LDS; q-tiles of 32 rows; full-row (256-key) S tile in LDS
// fp32 -> exact 2-pass softmax -> P bf16 -> PV MFMA -> O bf16 [n][c][e].
// ---------------------------------------------------------------------------
__global__ __launch_bounds__(256) void attn_kernel(
    const unsigned short* __restrict__ Q,
    const unsigned short* __restrict__ K,
    const unsigned short* __restrict__ Vt,
    unsigned short* __restrict__ O)
{
    __shared__ __align__(16) unsigned short Ks[256][72];   // [key][d]
    __shared__ __align__(16) unsigned short Vs[64][264];   // [d][key]
    __shared__ __align__(16) float          Ss[32][260];   // [qrow][key]
    __shared__ __align__(16) unsigned short Ps[32][264];   // [qrow][key]

    const int nh = blockIdx.x;           // n*4 + h
    const int n = nh >> 2, h = nh & 3;
    const int t = threadIdx.x, w = t >> 6, lane = t & 63;
    const int lr = lane & 15, lk = lane >> 4;

    const unsigned short* Kg = K + nh * 256 * 64;
    const unsigned short* Vg = Vt + nh * 64 * 256;
    const unsigned short* Qg = Q + nh * 256 * 64;

    // stage K (32 KB) + Vt (32 KB), fully coalesced reads
    {
        const uint4* ks = reinterpret_cast<const uint4*>(Kg);
        const uint4* vs = reinterpret_cast<const uint4*>(Vg);
        #pragma unroll
        for (int i = 0; i < 8; ++i) {
            int gb = t * 128 + i * 16;                     // byte offset
            uint4 kval = ks[gb >> 4];
            uint4 vval = vs[gb >> 4];
            char* kd = reinterpret_cast<char*>(&Ks[0][0]) + (gb >> 7) * 144 + (gb & 127);
            char* vd = reinterpret_cast<char*>(&Vs[0][0]) + (gb >> 9) * 528 + (gb & 511);
            *reinterpret_cast<uint4*>(kd) = kval;
            *reinterpret_cast<uint4*>(vd) = vval;
        }
    }
    __syncthreads();

    for (int qt = 0; qt < 8; ++qt) {
        // ---- S = (Q K^T) * HD^-0.5 : wave w covers keys [64w, 64w+64)
        f32x4 sacc[2][4] = {};
        s16x8 af[2][2];
        #pragma unroll
        for (int fm = 0; fm < 2; ++fm)
            #pragma unroll
            for (int kc = 0; kc < 2; ++kc)
                af[fm][kc] = *reinterpret_cast<const s16x8*>(
                    Qg + (qt * 32 + fm * 16 + lr) * 64 + kc * 32 + lk * 8);
        #pragma unroll
        for (int kc = 0; kc < 2; ++kc) {
            #pragma unroll
            for (int fn = 0; fn < 4; ++fn) {
                s16x8 bf = *reinterpret_cast<const s16x8*>(&Ks[w * 64 + fn * 16 + lr][kc * 32 + lk * 8]);
                #pragma unroll
                for (int fm = 0; fm < 2; ++fm)
                    sacc[fm][fn] = __builtin_amdgcn_mfma_f32_16x16x32_bf16(af[fm][kc], bf, sacc[fm][fn], 0, 0, 0);
            }
        }
        #pragma unroll
        for (int fm = 0; fm < 2; ++fm)
            #pragma unroll
            for (int fn = 0; fn < 4; ++fn)
                #pragma unroll
                for (int j = 0; j < 4; ++j)
                    Ss[fm * 16 + lk * 4 + j][w * 64 + fn * 16 + lr] = sacc[fm][fn][j] * 0.125f;
        __syncthreads();

        // ---- exact softmax: 8 threads per row, 32 cols each
        {
            int row = t >> 3, seg = t & 7;
            float4 v[8];
            const float4* srow = reinterpret_cast<const float4*>(&Ss[row][seg * 32]);
            #pragma unroll
            for (int i = 0; i < 8; ++i) v[i] = srow[i];
            float m = v[0].x;
            #pragma unroll
            for (int i = 0; i < 8; ++i)
                m = fmaxf(m, fmaxf(fmaxf(v[i].x, v[i].y), fmaxf(v[i].z, v[i].w)));
            m = fmaxf(m, __shfl_xor(m, 1));
            m = fmaxf(m, __shfl_xor(m, 2));
            m = fmaxf(m, __shfl_xor(m, 4));
            float s = 0.f;
            #pragma unroll
            for (int i = 0; i < 8; ++i) {
                v[i].x = exp2f((v[i].x - m) * 1.44269504f);
                v[i].y = exp2f((v[i].y - m) * 1.44269504f);
                v[i].z = exp2f((v[i].z - m) * 1.44269504f);
                v[i].w = exp2f((v[i].w - m) * 1.44269504f);
                s += (v[i].x + v[i].y) + (v[i].z + v[i].w);
            }
            s += __shfl_xor(s, 1);
            s += __shfl_xor(s, 2);
            s += __shfl_xor(s, 4);
            float r = 1.0f / s;
            #pragma unroll
            for (int i = 0; i < 4; ++i) {
                uint4 pk = { pack2(v[2 * i].x * r, v[2 * i].y * r),
                             pack2(v[2 * i].z * r, v[2 * i].w * r),
                             pack2(v[2 * i + 1].x * r, v[2 * i + 1].y * r),
                             pack2(v[2 * i + 1].z * r, v[2 * i + 1].w * r) };
                *reinterpret_cast<uint4*>(&Ps[row][seg * 32 + i * 8]) = pk;
            }
        }
        __syncthreads();

        // ---- O_tile = P @ V : wave w covers d-cols [16w, 16w+16)
        f32x4 oacc[2] = {};
        #pragma unroll
        for (int kc = 0; kc < 8; ++kc) {
            s16x8 bfr = *reinterpret_cast<const s16x8*>(&Vs[16 * w + lr][kc * 32 + lk * 8]);
            #pragma unroll
            for (int fm = 0; fm < 2; ++fm) {
                s16x8 afr = *reinterpret_cast<const s16x8*>(&Ps[fm * 16 + lr][kc * 32 + lk * 8]);
                oacc[fm] = __builtin_amdgcn_mfma_f32_16x16x32_bf16(afr, bfr, oacc[fm], 0, 0, 0);
            }
        }
        #pragma unroll
        for (int fm = 0; fm < 2; ++fm)
            #pragma unroll
            for (int j = 0; j < 4; ++j) {
                int c = qt * 32 + fm * 16 + lk * 4 + j;
                int e = h * 64 + 16 * w + lr;
                O[(n * 256 + c) * 256 + e] = f2bf(oacc[fm][j]);
            }
        __syncthreads();   // protect Ss/Ps for next q-tile
    }
}

// ---------------------------------------------------------------------------
extern "C" void kernel_launch(void* const* d_in, const int* in_sizes, int n_in,
                              void* d_out, int out_size, void* d_ws, size_t ws_size,
                              hipStream_t stream) {
    const float* x     = (const float*)d_in[0];
    const float* w_in  = (const float*)d_in[1];
    const float* b_in  = (const float*)d_in[2];
    const float* w_out = (const float*)d_in[3];
    const float* b_out = (const float*)d_in[4];
    float* out = (float*)d_out;

    char* ws = (char*)d_ws;
    unsigned short* tO = (unsigned short*)(ws);               // t, later O (aliased)
    unsigned short* Qw = (unsigned short*)(ws + (size_t)WS_SEG);
    unsigned short* Kw = (unsigned short*)(ws + (size_t)2 * WS_SEG);
    unsigned short* Vw = (unsigned short*)(ws + (size_t)3 * WS_SEG);

    gather_bf16<<<32768, 256, 0, stream>>>(x, tO);

    dim3 g1(1024, 12);   // M=131072/128, N=768/64
    gemm_bf16<0><<<g1, 256, 0, stream>>>(tO, w_in, b_in, Qw, Kw, Vw, nullptr);

    attn_kernel<<<2048, 256, 0, stream>>>(Qw, Kw, Vw, tO);   // O overwrites t

    dim3 g3(1024, 4);    // N=256/64
    gemm_bf16<1><<<g3, 256, 0, stream>>>(tO, w_out, b_out, nullptr, nullptr, nullptr, out);
}